// Round 1
// baseline (1464.840 us; speedup 1.0000x reference)
//
#include <hip/hip_runtime.h>

typedef __attribute__((ext_vector_type(8))) short bf16x8;
typedef __attribute__((ext_vector_type(4))) float f32x4;

__device__ __forceinline__ unsigned short f2bf(float f) {
    unsigned u = __float_as_uint(f);
    u += 0x7FFF + ((u >> 16) & 1);   // RNE
    return (unsigned short)(u >> 16);
}

// Convert 5 DxD f32 weight matrices (row-major [k][col]) to bf16 transposed [col][k].
__global__ void k_prep_wt(const float* __restrict__ Wa, const float* __restrict__ Wb,
                          const float* __restrict__ Wc, const float* __restrict__ Wd,
                          const float* __restrict__ We, unsigned short* __restrict__ wt) {
    int g = blockIdx.x * 256 + threadIdx.x;
    if (g >= 5 * 16384) return;
    int m = g >> 14, idx = g & 16383;
    int col = idx >> 7, k = idx & 127;
    const float* W = (m == 0) ? Wa : (m == 1) ? Wb : (m == 2) ? Wc : (m == 3) ? Wd : We;
    wt[g] = f2bf(W[k * 128 + col]);
}

// ---- Node GEMM: [Ah|Bh|Dh|Eh] = (h*norm) @ W + b,  one matrix per blockIdx.y ----
__global__ __launch_bounds__(256) void k_node_gemm(
    const float* __restrict__ h, const float* __restrict__ norm,
    const unsigned short* __restrict__ wt_all,
    const float* __restrict__ ba, const float* __restrict__ bb,
    const float* __restrict__ bd, const float* __restrict__ be,
    float* __restrict__ nodebuf, int N)
{
    __shared__ __align__(16) unsigned char wlds[32768];
    int y = blockIdx.y;                      // 0:Wa 1:Wb 2:Wd 3:We
    int wm = (y == 0) ? 0 : (y == 1) ? 1 : (y == 2) ? 3 : 4;
    const unsigned short* wt = wt_all + wm * 16384;
    int tid = threadIdx.x;
    // stage W^T into LDS, XOR-swizzled 16B chunks
    for (int c = tid; c < 2048; c += 256) {
        int byte = (c * 16) ^ (((c >> 4) & 7) << 4);
        *(bf16x8*)(wlds + byte) = *(const bf16x8*)((const short*)wt + c * 8);
    }
    __syncthreads();

    int wave = tid >> 6, lane = tid & 63;
    int lr = lane & 15, lk = lane >> 4;
    int rowbase = blockIdx.x * 256 + wave * 64;
    const float* bias = (y == 0) ? ba : (y == 1) ? bb : (y == 2) ? bd : be;
    float* outb = nodebuf + (size_t)y * N * 128;

    int rows[4]; float nrm[4];
#pragma unroll
    for (int rs = 0; rs < 4; ++rs) {
        int r = rowbase + rs * 16 + lr;
        rows[rs] = r < N ? r : N - 1;
        nrm[rs] = norm[rows[rs]];
    }

    f32x4 acc[4][8];
#pragma unroll
    for (int rs = 0; rs < 4; ++rs)
#pragma unroll
        for (int nt = 0; nt < 8; ++nt)
            acc[rs][nt] = (f32x4){0.f, 0.f, 0.f, 0.f};

#pragma unroll
    for (int kt = 0; kt < 4; ++kt) {
        int k0 = kt * 32 + lk * 8;
        bf16x8 afr[4];
#pragma unroll
        for (int rs = 0; rs < 4; ++rs) {
            const float* p = h + (size_t)rows[rs] * 128 + k0;
            f32x4 v0 = *(const f32x4*)p;
            f32x4 v1 = *(const f32x4*)(p + 4);
            float nv = nrm[rs];
            bf16x8 a;
#pragma unroll
            for (int i = 0; i < 4; ++i) a[i]     = (short)f2bf(v0[i] * nv);
#pragma unroll
            for (int i = 0; i < 4; ++i) a[4 + i] = (short)f2bf(v1[i] * nv);
            afr[rs] = a;
        }
#pragma unroll
        for (int nt = 0; nt < 8; ++nt) {
            int col = nt * 16 + lr;
            int byte = col * 256 + ((k0 * 2) ^ ((col & 7) << 4));
            bf16x8 b = *(bf16x8*)(wlds + byte);
#pragma unroll
            for (int rs = 0; rs < 4; ++rs)
                acc[rs][nt] = __builtin_amdgcn_mfma_f32_16x16x32_bf16(afr[rs], b, acc[rs][nt], 0, 0, 0);
        }
    }

#pragma unroll
    for (int nt = 0; nt < 8; ++nt) {
        int col = nt * 16 + lr;
        float bv = bias[col];
#pragma unroll
        for (int rs = 0; rs < 4; ++rs) {
#pragma unroll
            for (int j = 0; j < 4; ++j) {
                int r = rowbase + rs * 16 + lk * 4 + j;
                if (r < N) outb[(size_t)r * 128 + col] = acc[rs][nt][j] + bv;
            }
        }
    }
}

// ---- Edge kernel: Ce = e@Wc + bc; e_ij = Ce + Dh[src] + Eh[dst]; sigmoid; atomic seg-sums ----
__global__ __launch_bounds__(256) void k_edge(
    const float* __restrict__ e, const int* __restrict__ src, const int* __restrict__ dst,
    const unsigned short* __restrict__ wt_all, const float* __restrict__ bc,
    const float* __restrict__ Bh, const float* __restrict__ Dh, const float* __restrict__ Eh,
    float* __restrict__ e_out, float* __restrict__ num, float* __restrict__ den, int E)
{
    __shared__ __align__(16) unsigned char wlds[32768];
    __shared__ int s_src[256];
    __shared__ int s_dst[256];
    const unsigned short* wt = wt_all + 2 * 16384;   // Wc
    int tid = threadIdx.x;
    for (int c = tid; c < 2048; c += 256) {
        int byte = (c * 16) ^ (((c >> 4) & 7) << 4);
        *(bf16x8*)(wlds + byte) = *(const bf16x8*)((const short*)wt + c * 8);
    }
    int g = blockIdx.x * 256 + tid;
    int ge = g < E ? g : E - 1;
    s_src[tid] = src[ge];
    s_dst[tid] = dst[ge];
    __syncthreads();

    int wave = tid >> 6, lane = tid & 63;
    int lr = lane & 15, lk = lane >> 4;
    int rowbase = blockIdx.x * 256 + wave * 64;

    int rows[4];
#pragma unroll
    for (int rs = 0; rs < 4; ++rs) {
        int r = rowbase + rs * 16 + lr;
        rows[rs] = r < E ? r : E - 1;
    }

    f32x4 acc[4][8];
#pragma unroll
    for (int rs = 0; rs < 4; ++rs)
#pragma unroll
        for (int nt = 0; nt < 8; ++nt)
            acc[rs][nt] = (f32x4){0.f, 0.f, 0.f, 0.f};

#pragma unroll
    for (int kt = 0; kt < 4; ++kt) {
        int k0 = kt * 32 + lk * 8;
        bf16x8 afr[4];
#pragma unroll
        for (int rs = 0; rs < 4; ++rs) {
            const float* p = e + (size_t)rows[rs] * 128 + k0;
            f32x4 v0 = *(const f32x4*)p;
            f32x4 v1 = *(const f32x4*)(p + 4);
            bf16x8 a;
#pragma unroll
            for (int i = 0; i < 4; ++i) a[i]     = (short)f2bf(v0[i]);
#pragma unroll
            for (int i = 0; i < 4; ++i) a[4 + i] = (short)f2bf(v1[i]);
            afr[rs] = a;
        }
#pragma unroll
        for (int nt = 0; nt < 8; ++nt) {
            int col = nt * 16 + lr;
            int byte = col * 256 + ((k0 * 2) ^ ((col & 7) << 4));
            bf16x8 b = *(bf16x8*)(wlds + byte);
#pragma unroll
            for (int rs = 0; rs < 4; ++rs)
                acc[rs][nt] = __builtin_amdgcn_mfma_f32_16x16x32_bf16(afr[rs], b, acc[rs][nt], 0, 0, 0);
        }
    }

#pragma unroll
    for (int nt = 0; nt < 8; ++nt) {
        int col = nt * 16 + lr;
        float bcv = bc[col];
#pragma unroll
        for (int rs = 0; rs < 4; ++rs) {
#pragma unroll
            for (int j = 0; j < 4; ++j) {
                int li = wave * 64 + rs * 16 + lk * 4 + j;
                int r = blockIdx.x * 256 + li;
                if (r < E) {
                    int s = s_src[li], d = s_dst[li];
                    float x = acc[rs][nt][j] + bcv + Dh[s * 128 + col] + Eh[d * 128 + col];
                    e_out[(size_t)r * 128 + col] = x;
                    float sig = 1.f / (1.f + __expf(-x));
                    atomicAdd(num + d * 128 + col, sig * Bh[s * 128 + col]);
                    atomicAdd(den + d * 128 + col, sig);
                }
            }
        }
    }
}

__global__ void k_deg(const int* __restrict__ dst, float* __restrict__ deg, int E) {
    int g = blockIdx.x * 256 + threadIdx.x;
    if (g < E) atomicAdd(deg + dst[g], 1.0f);
}

__global__ void k_final(const float* __restrict__ h, const float* __restrict__ norm,
                        const float* __restrict__ Ah, const float* __restrict__ num,
                        const float* __restrict__ den, const float* __restrict__ deg,
                        float* __restrict__ out, int N) {
    int g = blockIdx.x * 256 + threadIdx.x;
    if (g >= N * 128) return;
    int row = g >> 7;
    float nv = norm[row];
    float hv = (deg[row] > 0.f) ? (Ah[g] + num[g] / (den[g] + 1e-6f)) : (h[g] * nv);
    out[g] = hv * nv;
}

extern "C" void kernel_launch(void* const* d_in, const int* in_sizes, int n_in,
                              void* d_out, int out_size, void* d_ws, size_t ws_size,
                              hipStream_t stream) {
    const float* h    = (const float*)d_in[0];
    const float* e    = (const float*)d_in[1];
    const float* norm = (const float*)d_in[2];
    const int*   src  = (const int*)d_in[3];
    const int*   dst  = (const int*)d_in[4];
    const float* Wa = (const float*)d_in[5];
    const float* ba = (const float*)d_in[6];
    const float* Wb = (const float*)d_in[7];
    const float* bb = (const float*)d_in[8];
    const float* Wc = (const float*)d_in[9];
    const float* bc = (const float*)d_in[10];
    const float* Wd = (const float*)d_in[11];
    const float* bd = (const float*)d_in[12];
    const float* We = (const float*)d_in[13];
    const float* be = (const float*)d_in[14];

    int N = in_sizes[0] / 128;
    int E = in_sizes[3];

    float* out_h = (float*)d_out;
    float* out_e = out_h + (size_t)N * 128;

    char* ws = (char*)d_ws;
    unsigned short* wt = (unsigned short*)ws;                 // 5*16384 bf16 = 160KB
    float* nodebuf = (float*)(ws + 5 * 16384 * 2);            // Ah|Bh|Dh|Eh, 4*N*128 f32
    float* Ah  = nodebuf;
    float* Bh2 = nodebuf + (size_t)1 * N * 128;
    float* Dh2 = nodebuf + (size_t)2 * N * 128;
    float* Eh2 = nodebuf + (size_t)3 * N * 128;
    float* num = nodebuf + (size_t)4 * N * 128;
    float* den = num + (size_t)N * 128;
    float* deg = den + (size_t)N * 128;

    // zero num, den, deg (contiguous)
    hipMemsetAsync(num, 0, ((size_t)2 * N * 128 + N) * sizeof(float), stream);

    k_prep_wt<<<(5 * 16384 + 255) / 256, 256, 0, stream>>>(Wa, Wb, Wc, Wd, We, wt);
    k_node_gemm<<<dim3((N + 255) / 256, 4), 256, 0, stream>>>(h, norm, wt, ba, bb, bd, be, nodebuf, N);
    k_deg<<<(E + 255) / 256, 256, 0, stream>>>(dst, deg, E);
    k_edge<<<(E + 255) / 256, 256, 0, stream>>>(e, src, dst, wt, bc, Bh2, Dh2, Eh2, out_e, num, den, E);
    k_final<<<((N * 128) + 255) / 256, 256, 0, stream>>>(h, norm, Ah, num, den, deg, out_h, N);
}